// Round 21
// baseline (325.921 us; speedup 1.0000x reference)
//
#include <hip/hip_runtime.h>
#include <hip/hip_fp16.h>
#include <math.h>

#define N 16384
#define K 32
#define D 16
#define S 2048
#define E 500000
#define EPSF 1e-6f
#define B 256

// ---- workspace layout (float offsets) ----
#define OFF_Z      0                       // K*N (col-major softmax result)
#define OFF_CSPART (K*N)                   // 64*32 colsum partials
#define OFF_AZCP   (OFF_CSPART + 2048)     // 64*512 partial AZC planes
#define OFF_EP     (OFF_AZCP + 32768)      // N rows x 64B: 16 fp16 dims + fp32 beta + pad
#define OFF_XST    (OFF_EP + N*16)         // D*S transposed samples (fp32, pairwise)
#define OFF_BS     (OFF_XST + D*S)         // S sampled betas
#define OFF_PD1    (OFF_BS + S)            // 512 pairwise partials
#define OFF_PD2    (OFF_PD1 + 512)         // 1024 edge partials

#define GPAIR 512
#define GEDGE 1024
#define GPE   (GPAIR + GEDGE)
#define ROWS  4

// ===== x16 WORK-AMPLIFICATION PROBE #2 (measurement round, r20 kernels) =====
// Idempotent reps; `zero`==0 at runtime, rep*zero offsets defeat hoist/CSE.
// Final memory state bit-identical to the unamplified r20 kernel.

__device__ __forceinline__ float block_reduce_sum(float v, float* sdata) {
    int tid = threadIdx.x;
    sdata[tid] = v;
    __syncthreads();
    for (int s = B >> 1; s > 0; s >>= 1) {
        if (tid < s) sdata[tid] += sdata[tid + s];
        __syncthreads();
    }
    return sdata[0];
}

__global__ __launch_bounds__(B) void k_ab(
    const float* __restrict__ Zp, const float* __restrict__ Gate,
    const int* __restrict__ sample_idx, const float* __restrict__ A,
    float* __restrict__ ws, int reps, int zero)
{
    __shared__ __align__(16) float sf[256 * 33 + 256];
    int tid = threadIdx.x, bid = blockIdx.x;
    if (bid < 64) {
        for (int rep = 0; rep < reps; ++rep) {
            const float* Zp_r = Zp + (size_t)rep * zero;
            const float* Gate_r = Gate + (size_t)rep * zero;
            float* ws_r = ws + (size_t)rep * zero;
            int n = bid * B + tid;
            float z[K];
            float m = -1e30f;
#pragma unroll
            for (int k = 0; k < K; ++k) { z[k] = Zp_r[k * N + n]; m = fmaxf(m, z[k]); }
            float s = 0.f;
#pragma unroll
            for (int k = 0; k < K; ++k) { z[k] = __expf(z[k] - m); s += z[k]; }
            float inv = 1.f / s;
#pragma unroll
            for (int k = 0; k < K; ++k) { z[k] *= inv; ws_r[OFF_Z + k * N + n] = z[k]; }
            float t[K];
            const float4* gp = reinterpret_cast<const float4*>(Gate_r + (size_t)n * K);
#pragma unroll
            for (int q = 0; q < K / 4; ++q) {
                float4 g = gp[q];
                t[4*q+0] = z[4*q+0] / (1.f + __expf(-g.x));
                t[4*q+1] = z[4*q+1] / (1.f + __expf(-g.y));
                t[4*q+2] = z[4*q+2] / (1.f + __expf(-g.z));
                t[4*q+3] = z[4*q+3] / (1.f + __expf(-g.w));
            }
#pragma unroll
            for (int k = 0; k < K; ++k) sf[tid * 33 + k] = t[k];
            __syncthreads();
            int kk = tid & 31, rg = tid >> 5;
            float acc = 0.f;
#pragma unroll
            for (int r = 0; r < 32; ++r) acc += sf[(rg * 32 + r) * 33 + kk];
            sf[256 * 33 + rg * 32 + kk] = acc;
            __syncthreads();
            if (rg == 0) {
                float tot = 0.f;
#pragma unroll
                for (int g2 = 0; g2 < 8; ++g2) tot += sf[256 * 33 + g2 * 32 + kk];
                ws_r[OFF_CSPART + bid * 32 + kk] = tot;
            }
            __syncthreads();
        }
    } else {
        for (int rep = 0; rep < reps; ++rep) {
            const float* Zp_r = Zp + (size_t)rep * zero;
            const float* Gate_r = Gate + (size_t)rep * zero;
            float* ws_r = ws + (size_t)rep * zero;
            float* sZ = sf;
            float* sT = sf + 1024;
            float* sM = sf + 2048;
            int slot = tid >> 3, sub = tid & 7;
            int idx = sample_idx[(bid - 64) * 32 + slot + rep * zero];
            float za[4];
            float m = -1e30f;
#pragma unroll
            for (int q = 0; q < 4; ++q) {
                za[q] = Zp_r[(sub + 8 * q) * N + idx];
                m = fmaxf(m, za[q]);
            }
#pragma unroll
            for (int off = 1; off < 8; off <<= 1) m = fmaxf(m, __shfl_xor(m, off, 8));
            float ssum = 0.f;
#pragma unroll
            for (int q = 0; q < 4; ++q) { za[q] = __expf(za[q] - m); ssum += za[q]; }
#pragma unroll
            for (int off = 1; off < 8; off <<= 1) ssum += __shfl_xor(ssum, off, 8);
            float inv = 1.f / ssum;
#pragma unroll
            for (int q = 0; q < 4; ++q) {
                int a = sub + 8 * q;
                float zv = za[q] * inv;
                float g = Gate_r[(size_t)idx * K + a];
                sZ[slot * 32 + a] = zv;
                sT[slot * 32 + a] = zv / (1.f + __expf(-g));
            }
            __syncthreads();
#pragma unroll
            for (int e4 = 0; e4 < 4; ++e4) {
                int ent = tid + e4 * B;
                int a = ent >> 5, b = ent & 31;
                float acc = 0.f;
#pragma unroll
                for (int sl = 0; sl < 32; ++sl) acc += sZ[sl * 32 + a] * sT[sl * 32 + b];
                sM[ent & 1023] = acc;
            }
            __syncthreads();
#pragma unroll
            for (int e2 = 0; e2 < 2; ++e2) {
                int ent = tid + e2 * B;
                int d = ent >> 5, b = ent & 31;
                float azc = 0.f;
#pragma unroll
                for (int a = 0; a < K; ++a) azc += A[d * K + a + rep * zero] * sM[a * 32 + b];
                ws_r[OFF_AZCP + (size_t)(bid - 64) * 512 + ent] = azc;
            }
            __syncthreads();
        }
    }
}

__global__ __launch_bounds__(B) void k_x(
    const float* __restrict__ beta, const int* __restrict__ sample_idx,
    float* __restrict__ ws, int reps, int zero)
{
    __shared__ float sA[512];
    __shared__ float scs[32];
    int tid = threadIdx.x, bid = blockIdx.x;
    for (int rep = 0; rep < reps; ++rep) {
        float* ws_r = ws + (size_t)rep * zero;
        if (tid < 32) {
            float cs = 0.f;
#pragma unroll
            for (int p = 0; p < 64; ++p) cs += ws_r[OFF_CSPART + p * 32 + tid];
            scs[tid] = cs;
        }
        float a0 = 0.f, a1 = 0.f;
#pragma unroll
        for (int p = 0; p < 64; ++p) {
            a0 += ws_r[OFF_AZCP + (size_t)p * 512 + tid];
            a1 += ws_r[OFF_AZCP + (size_t)p * 512 + tid + B];
        }
        __syncthreads();
        sA[tid]     = a0 / scs[tid & 31];
        sA[tid + B] = a1 / scs[tid & 31];
        __syncthreads();
        if (bid < 256) {
            int n = bid * 64 + (tid >> 2);
            int dq = tid & 3;
            float x0 = 0.f, x1 = 0.f, x2 = 0.f, x3 = 0.f;
#pragma unroll
            for (int k = 0; k < K; ++k) {
                float zk = ws_r[OFF_Z + k * N + n];
                x0 = fmaf(sA[(dq * 4 + 0) * 32 + k], zk, x0);
                x1 = fmaf(sA[(dq * 4 + 1) * 32 + k], zk, x1);
                x2 = fmaf(sA[(dq * 4 + 2) * 32 + k], zk, x2);
                x3 = fmaf(sA[(dq * 4 + 3) * 32 + k], zk, x3);
            }
            __half2 h01 = __floats2half2_rn(x0, x1);
            __half2 h23 = __floats2half2_rn(x2, x3);
            uint2 w;
            w.x = *reinterpret_cast<unsigned int*>(&h01);
            w.y = *reinterpret_cast<unsigned int*>(&h23);
            char* rowp = reinterpret_cast<char*>(ws_r + OFF_EP) + (size_t)n * 64;
            *reinterpret_cast<uint2*>(rowp + dq * 8) = w;
            if (dq == 0) *reinterpret_cast<float*>(rowp + 32) = beta[n + rep * zero];
        } else {
            int slot = tid >> 3, sub = tid & 7;
            int sslot = (bid - 256) * 32 + slot;
            int idx = sample_idx[sslot + rep * zero];
            float x0 = 0.f, x1 = 0.f;
#pragma unroll
            for (int k = 0; k < K; ++k) {
                float zk = ws_r[OFF_Z + (size_t)k * N + idx];
                x0 = fmaf(sA[(2 * sub + 0) * 32 + k], zk, x0);
                x1 = fmaf(sA[(2 * sub + 1) * 32 + k], zk, x1);
            }
            ws_r[OFF_XST + (size_t)(2 * sub + 0) * S + sslot] = x0;
            ws_r[OFF_XST + (size_t)(2 * sub + 1) * S + sslot] = x1;
            if (sub == 0) ws_r[OFF_BS + sslot] = beta[idx + rep * zero];
        }
        __syncthreads();
    }
}

__device__ __forceinline__ float qdiff8(unsigned int ax, unsigned int ay,
                                        unsigned int az, unsigned int aw,
                                        unsigned int bx, unsigned int by,
                                        unsigned int bz, unsigned int bw)
{
    float part = 0.f, d;
    float2 p, r;
    p = __half22float2(*reinterpret_cast<__half2*>(&ax));
    r = __half22float2(*reinterpret_cast<__half2*>(&bx));
    d = p.x - r.x + EPSF; part = fmaf(d, d, part);
    d = p.y - r.y + EPSF; part = fmaf(d, d, part);
    p = __half22float2(*reinterpret_cast<__half2*>(&ay));
    r = __half22float2(*reinterpret_cast<__half2*>(&by));
    d = p.x - r.x + EPSF; part = fmaf(d, d, part);
    d = p.y - r.y + EPSF; part = fmaf(d, d, part);
    p = __half22float2(*reinterpret_cast<__half2*>(&az));
    r = __half22float2(*reinterpret_cast<__half2*>(&bz));
    d = p.x - r.x + EPSF; part = fmaf(d, d, part);
    d = p.y - r.y + EPSF; part = fmaf(d, d, part);
    p = __half22float2(*reinterpret_cast<__half2*>(&aw));
    r = __half22float2(*reinterpret_cast<__half2*>(&bw));
    d = p.x - r.x + EPSF; part = fmaf(d, d, part);
    d = p.y - r.y + EPSF; part = fmaf(d, d, part);
    return part;
}

__global__ __launch_bounds__(B) void k_pe(
    const int* __restrict__ sparse_i, const int* __restrict__ sparse_j,
    float* __restrict__ ws, int reps, int zero)
{
    __shared__ float sdata[256];
    int tid = threadIdx.x, bid = blockIdx.x;

    if (bid < GPAIR) {
        for (int rep = 0; rep < reps; ++rep) {
            float* ws_r = ws + (size_t)rep * zero;
            int r0 = bid * ROWS;
            float xr[ROWS][D];
            float nr[ROWS], br[ROWS];
#pragma unroll
            for (int r = 0; r < ROWS; ++r) {
                float nn = 0.f;
#pragma unroll
                for (int d = 0; d < D; ++d) {
                    float v = ws_r[OFF_XST + (size_t)d * S + r0 + r] + EPSF;
                    xr[r][d] = v;
                    nn = fmaf(v, v, nn);
                }
                nr[r] = nn;
                br[r] = ws_r[OFF_BS + r0 + r];
            }
            float accP = 0.f;
            for (int t = tid; t < S; t += B) {
                float xt[D];
                float nv = 0.f;
#pragma unroll
                for (int d = 0; d < D; ++d) {
                    xt[d] = ws_r[OFF_XST + (size_t)d * S + t];
                    nv = fmaf(xt[d], xt[d], nv);
                }
                float bt = ws_r[OFF_BS + t];
#pragma unroll
                for (int r = 0; r < ROWS; ++r) {
                    float dot = 0.f;
#pragma unroll
                    for (int d = 0; d < D; ++d) dot = fmaf(xr[r][d], xt[d], dot);
                    float d2 = fmaxf(fmaf(-2.f, dot, nr[r] + nv), 0.f);
                    float v = __expf(br[r] + bt - sqrtf(d2));
                    accP += (r0 + r == t) ? 0.f : v;
                }
            }
            __syncthreads();
            float totP = block_reduce_sum(accP, sdata);
            if (tid == 0) ws_r[OFF_PD1 + bid] = totP;
            __syncthreads();
        }
    } else {
        for (int rep = 0; rep < reps; ++rep) {
            float* ws_r = ws + (size_t)rep * zero;
            int quad = tid >> 2, q = tid & 3;
            const char* ep = reinterpret_cast<const char*>(ws_r + OFF_EP);
            float accE = 0.f;
            const int stride = GEDGE * 64;
            for (int e1 = (bid - GPAIR) * 64 + quad; e1 < E; e1 += 2 * stride) {
                int e2 = e1 + stride;
                bool has2 = (e2 < E);
                int i1 = sparse_i[e1 + rep * zero], j1 = sparse_j[e1 + rep * zero];
                int i2 = has2 ? sparse_i[e2 + rep * zero] : i1;
                int j2 = has2 ? sparse_j[e2 + rep * zero] : j1;
                uint4 a1 = *reinterpret_cast<const uint4*>(ep + (size_t)i1 * 64 + q * 16);
                uint4 b1 = *reinterpret_cast<const uint4*>(ep + (size_t)j1 * 64 + q * 16);
                uint4 a2 = *reinterpret_cast<const uint4*>(ep + (size_t)i2 * 64 + q * 16);
                uint4 b2 = *reinterpret_cast<const uint4*>(ep + (size_t)j2 * 64 + q * 16);
                float p1 = qdiff8(a1.x, a1.y, a1.z, a1.w, b1.x, b1.y, b1.z, b1.w);
                float p2 = qdiff8(a2.x, a2.y, a2.z, a2.w, b2.x, b2.y, b2.z, b2.w);
                p1 = (q < 2) ? p1 : 0.f;
                p2 = (q < 2) ? p2 : 0.f;
                float pb1 = (q == 2) ? (__uint_as_float(a1.x) + __uint_as_float(b1.x)) : 0.f;
                float pb2 = (q == 2) ? (__uint_as_float(a2.x) + __uint_as_float(b2.x)) : 0.f;
                p1 += __shfl_xor(p1, 1, 4);  p1 += __shfl_xor(p1, 2, 4);
                p2 += __shfl_xor(p2, 1, 4);  p2 += __shfl_xor(p2, 2, 4);
                pb1 += __shfl_xor(pb1, 1, 4); pb1 += __shfl_xor(pb1, 2, 4);
                pb2 += __shfl_xor(pb2, 1, 4); pb2 += __shfl_xor(pb2, 2, 4);
                if (q == 0) {
                    accE += pb1 - sqrtf(p1);
                    if (has2) accE += pb2 - sqrtf(p2);
                }
            }
            __syncthreads();
            float totE = block_reduce_sum(accE, sdata);
            if (tid == 0) ws_r[OFF_PD2 + (bid - GPAIR)] = totE;
            __syncthreads();
        }
    }
}

__global__ __launch_bounds__(B) void k_fin(float* __restrict__ ws,
                                           float* __restrict__ out)
{
    __shared__ float sdata[256];
    int tid = threadIdx.x;
    float v1 = ws[OFF_PD1 + tid] + ws[OFF_PD1 + tid + 256];
    float s1 = block_reduce_sum(v1, sdata);
    __syncthreads();
    float v2 = ws[OFF_PD2 + tid] + ws[OFF_PD2 + tid + 256]
             + ws[OFF_PD2 + tid + 512] + ws[OFF_PD2 + tid + 768];
    float s2 = block_reduce_sum(v2, sdata);
    if (tid == 0) {
        float e = expf(1.0f);
        out[0] = s2 - 0.5f * e * e * s1;
    }
}

extern "C" void kernel_launch(void* const* d_in, const int* in_sizes, int n_in,
                              void* d_out, int out_size, void* d_ws, size_t ws_size,
                              hipStream_t stream) {
    const float* beta = (const float*)d_in[0];
    const float* A    = (const float*)d_in[1];
    const float* Zp   = (const float*)d_in[2];
    const float* Gate = (const float*)d_in[3];
    const int* sample_idx = (const int*)d_in[4];
    const int* sparse_i   = (const int*)d_in[5];
    const int* sparse_j   = (const int*)d_in[6];
    float* ws  = (float*)d_ws;
    float* out = (float*)d_out;

    // x16 amplification; `zero` is runtime-0 (n_in is always 7) so reps
    // cannot be collapsed by the compiler.
    int reps = 16;
    int zero = (n_in == 7) ? 0 : 1;

    k_ab <<<128, B, 0, stream>>>(Zp, Gate, sample_idx, A, ws, reps, zero);
    k_x  <<<320, B, 0, stream>>>(beta, sample_idx, ws, reps, zero);
    k_pe <<<GPE, B, 0, stream>>>(sparse_i, sparse_j, ws, reps, zero);
    k_fin<<<1,   B, 0, stream>>>(ws, out);
}

// Round 22
// 37.609 us; speedup vs baseline: 8.6659x; 8.6659x over previous
//
#include <hip/hip_runtime.h>
#include <hip/hip_fp16.h>
#include <math.h>

#define N 16384
#define K 32
#define D 16
#define S 2048
#define E 500000
#define EPSF 1e-6f
#define B 256

// ---- workspace layout (float offsets) ----
#define OFF_Z      0                       // K*N (col-major softmax result)
#define OFF_CSPART (K*N)                   // 64*32 colsum partials
#define OFF_AZCP   (OFF_CSPART + 2048)     // 64*512 partial AZC planes
#define OFF_EP     (OFF_AZCP + 32768)      // N rows x 64B: 16 fp16 dims + fp32 beta + pad
#define OFF_XST    (OFF_EP + N*16)         // D*S transposed samples (fp32, pairwise)
#define OFF_BS     (OFF_XST + D*S)         // S sampled betas
#define OFF_TN     (OFF_BS + S)            // S precomputed |xt|^2 (no-eps, exact)
#define OFF_PD1    (OFF_TN + S)            // 512 pairwise partials
#define OFF_PD2    (OFF_PD1 + 512)         // 1024 edge partials

#define GPAIR 512
#define GEDGE 1024
#define GPE   (GPAIR + GEDGE)
#define ROWS  4

__device__ __forceinline__ float block_reduce_sum(float v, float* sdata) {
    int tid = threadIdx.x;
    sdata[tid] = v;
    __syncthreads();
    for (int s = B >> 1; s > 0; s >>= 1) {
        if (tid < s) sdata[tid] += sdata[tid + s];
        __syncthreads();
    }
    return sdata[0];
}

// K1: blocks 0..63 softmax cols + ZTG colsum partials;
//     blocks 64..127: Mpart partials + per-block A@Mp -> AZCpart plane.
__global__ __launch_bounds__(B) void k_ab(
    const float* __restrict__ Zp, const float* __restrict__ Gate,
    const int* __restrict__ sample_idx, const float* __restrict__ A,
    float* __restrict__ ws)
{
    __shared__ __align__(16) float sf[256 * 33 + 256];
    int tid = threadIdx.x, bid = blockIdx.x;
    if (bid < 64) {
        int n = bid * B + tid;
        float z[K];
        float m = -1e30f;
#pragma unroll
        for (int k = 0; k < K; ++k) { z[k] = Zp[k * N + n]; m = fmaxf(m, z[k]); }
        float s = 0.f;
#pragma unroll
        for (int k = 0; k < K; ++k) { z[k] = __expf(z[k] - m); s += z[k]; }
        float inv = 1.f / s;
#pragma unroll
        for (int k = 0; k < K; ++k) { z[k] *= inv; ws[OFF_Z + k * N + n] = z[k]; }
        float t[K];
        const float4* gp = reinterpret_cast<const float4*>(Gate + (size_t)n * K);
#pragma unroll
        for (int q = 0; q < K / 4; ++q) {
            float4 g = gp[q];
            t[4*q+0] = z[4*q+0] / (1.f + __expf(-g.x));
            t[4*q+1] = z[4*q+1] / (1.f + __expf(-g.y));
            t[4*q+2] = z[4*q+2] / (1.f + __expf(-g.z));
            t[4*q+3] = z[4*q+3] / (1.f + __expf(-g.w));
        }
#pragma unroll
        for (int k = 0; k < K; ++k) sf[tid * 33 + k] = t[k];
        __syncthreads();
        int kk = tid & 31, rg = tid >> 5;
        float acc = 0.f;
#pragma unroll
        for (int r = 0; r < 32; ++r) acc += sf[(rg * 32 + r) * 33 + kk];
        sf[256 * 33 + rg * 32 + kk] = acc;
        __syncthreads();
        if (rg == 0) {
            float tot = 0.f;
#pragma unroll
            for (int g2 = 0; g2 < 8; ++g2) tot += sf[256 * 33 + g2 * 32 + kk];
            ws[OFF_CSPART + bid * 32 + kk] = tot;
        }
    } else {
        // 32 samples per block, 8 threads per sample -> Mp in LDS -> A@Mp plane
        float* sZ = sf;           // 32*32
        float* sT = sf + 1024;    // 32*32
        float* sM = sf + 2048;    // 32*32 (Mp)
        int slot = tid >> 3, sub = tid & 7;
        int idx = sample_idx[(bid - 64) * 32 + slot];
        float za[4];
        float m = -1e30f;
#pragma unroll
        for (int q = 0; q < 4; ++q) {
            za[q] = Zp[(sub + 8 * q) * N + idx];
            m = fmaxf(m, za[q]);
        }
#pragma unroll
        for (int off = 1; off < 8; off <<= 1) m = fmaxf(m, __shfl_xor(m, off, 8));
        float ssum = 0.f;
#pragma unroll
        for (int q = 0; q < 4; ++q) { za[q] = __expf(za[q] - m); ssum += za[q]; }
#pragma unroll
        for (int off = 1; off < 8; off <<= 1) ssum += __shfl_xor(ssum, off, 8);
        float inv = 1.f / ssum;
#pragma unroll
        for (int q = 0; q < 4; ++q) {
            int a = sub + 8 * q;
            float zv = za[q] * inv;
            float g = Gate[(size_t)idx * K + a];
            sZ[slot * 32 + a] = zv;
            sT[slot * 32 + a] = zv / (1.f + __expf(-g));
        }
        __syncthreads();
#pragma unroll
        for (int e4 = 0; e4 < 4; ++e4) {
            int ent = tid + e4 * B;
            int a = ent >> 5, b = ent & 31;
            float acc = 0.f;
#pragma unroll
            for (int sl = 0; sl < 32; ++sl) acc += sZ[sl * 32 + a] * sT[sl * 32 + b];
            sM[ent & 1023] = acc;
        }
        __syncthreads();
#pragma unroll
        for (int e2 = 0; e2 < 2; ++e2) {
            int ent = tid + e2 * B;
            int d = ent >> 5, b = ent & 31;
            float azc = 0.f;
#pragma unroll
            for (int a = 0; a < K; ++a) azc += A[d * K + a] * sM[a * 32 + b];
            ws[OFF_AZCP + (size_t)(bid - 64) * 512 + ent] = azc;
        }
    }
}

// K2 (grid 320): prologue reduces 64 AZCpart planes + colsum -> AZC in LDS.
// Blocks 0..255 -> packed edge rows (fp16 dims + fp32 beta, one 64B line/row);
// 256..319 -> XST (fp32 transposed samples) + bs + precomputed |xt|^2.
__global__ __launch_bounds__(B) void k_x(
    const float* __restrict__ beta, const int* __restrict__ sample_idx,
    float* __restrict__ ws)
{
    __shared__ float sA[512];
    __shared__ float scs[32];
    int tid = threadIdx.x, bid = blockIdx.x;
    if (tid < 32) {
        float cs = 0.f;
#pragma unroll
        for (int p = 0; p < 64; ++p) cs += ws[OFF_CSPART + p * 32 + tid];
        scs[tid] = cs;
    }
    float a0 = 0.f, a1 = 0.f;
#pragma unroll
    for (int p = 0; p < 64; ++p) {
        a0 += ws[OFF_AZCP + (size_t)p * 512 + tid];
        a1 += ws[OFF_AZCP + (size_t)p * 512 + tid + B];
    }
    __syncthreads();
    sA[tid]     = a0 / scs[tid & 31];
    sA[tid + B] = a1 / scs[tid & 31];
    __syncthreads();
    if (bid < 256) {
        int n = bid * 64 + (tid >> 2);
        int dq = tid & 3;
        float x0 = 0.f, x1 = 0.f, x2 = 0.f, x3 = 0.f;
#pragma unroll
        for (int k = 0; k < K; ++k) {
            float zk = ws[OFF_Z + k * N + n];
            x0 = fmaf(sA[(dq * 4 + 0) * 32 + k], zk, x0);
            x1 = fmaf(sA[(dq * 4 + 1) * 32 + k], zk, x1);
            x2 = fmaf(sA[(dq * 4 + 2) * 32 + k], zk, x2);
            x3 = fmaf(sA[(dq * 4 + 3) * 32 + k], zk, x3);
        }
        // pack 4 dims -> 2 half2 words; row = 64B: halves[16] | beta | pad
        __half2 h01 = __floats2half2_rn(x0, x1);
        __half2 h23 = __floats2half2_rn(x2, x3);
        uint2 w;
        w.x = *reinterpret_cast<unsigned int*>(&h01);
        w.y = *reinterpret_cast<unsigned int*>(&h23);
        char* rowp = reinterpret_cast<char*>(ws + OFF_EP) + (size_t)n * 64;
        *reinterpret_cast<uint2*>(rowp + dq * 8) = w;
        if (dq == 0) *reinterpret_cast<float*>(rowp + 32) = beta[n];
    } else {
        int slot = tid >> 3, sub = tid & 7;
        int sslot = (bid - 256) * 32 + slot;
        int idx = sample_idx[sslot];
        float x0 = 0.f, x1 = 0.f;
#pragma unroll
        for (int k = 0; k < K; ++k) {
            float zk = ws[OFF_Z + (size_t)k * N + idx];
            x0 = fmaf(sA[(2 * sub + 0) * 32 + k], zk, x0);
            x1 = fmaf(sA[(2 * sub + 1) * 32 + k], zk, x1);
        }
        ws[OFF_XST + (size_t)(2 * sub + 0) * S + sslot] = x0;
        ws[OFF_XST + (size_t)(2 * sub + 1) * S + sslot] = x1;
        // precompute |xt|^2 (no eps): reduce x0^2+x1^2 over the 8 sub-lanes
        float nn = fmaf(x0, x0, x1 * x1);
        nn += __shfl_xor(nn, 1, 8);
        nn += __shfl_xor(nn, 2, 8);
        nn += __shfl_xor(nn, 4, 8);
        if (sub == 0) {
            ws[OFF_BS + sslot] = beta[idx];
            ws[OFF_TN + sslot] = nn;
        }
    }
}

__device__ __forceinline__ float qdiff8(unsigned int ax, unsigned int ay,
                                        unsigned int az, unsigned int aw,
                                        unsigned int bx, unsigned int by,
                                        unsigned int bz, unsigned int bw)
{
    float part = 0.f, d;
    float2 p, r;
    p = __half22float2(*reinterpret_cast<__half2*>(&ax));
    r = __half22float2(*reinterpret_cast<__half2*>(&bx));
    d = p.x - r.x + EPSF; part = fmaf(d, d, part);
    d = p.y - r.y + EPSF; part = fmaf(d, d, part);
    p = __half22float2(*reinterpret_cast<__half2*>(&ay));
    r = __half22float2(*reinterpret_cast<__half2*>(&by));
    d = p.x - r.x + EPSF; part = fmaf(d, d, part);
    d = p.y - r.y + EPSF; part = fmaf(d, d, part);
    p = __half22float2(*reinterpret_cast<__half2*>(&az));
    r = __half22float2(*reinterpret_cast<__half2*>(&bz));
    d = p.x - r.x + EPSF; part = fmaf(d, d, part);
    d = p.y - r.y + EPSF; part = fmaf(d, d, part);
    p = __half22float2(*reinterpret_cast<__half2*>(&aw));
    r = __half22float2(*reinterpret_cast<__half2*>(&bw));
    d = p.x - r.x + EPSF; part = fmaf(d, d, part);
    d = p.y - r.y + EPSF; part = fmaf(d, d, part);
    return part;
}

// K3 (grid 1536): blocks 0..511 pairwise (4 rows in registers, precomputed
// t-norms); blocks 512..1535 edges: 2-LANE scheme — lane q in {0,1} of each
// pair handles halves q*8..q*8+7 of rows i,j; all lanes productive (was 4-lane
// with 2 idle), 2x16B loads/edge, width-2 shuffle, q==0 adds betas+sqrt.
__global__ __launch_bounds__(B) void k_pe(
    const int* __restrict__ sparse_i, const int* __restrict__ sparse_j,
    float* __restrict__ ws)
{
    __shared__ float sdata[256];
    int tid = threadIdx.x, bid = blockIdx.x;

    if (bid < GPAIR) {
        int r0 = bid * ROWS;
        float xr[ROWS][D];
        float nr[ROWS], br[ROWS];
#pragma unroll
        for (int r = 0; r < ROWS; ++r) {
            float nn = 0.f;
#pragma unroll
            for (int d = 0; d < D; ++d) {
                float v = ws[OFF_XST + (size_t)d * S + r0 + r] + EPSF;
                xr[r][d] = v;
                nn = fmaf(v, v, nn);
            }
            nr[r] = nn;   // |xr+eps|^2 (exact row-side value)
            br[r] = ws[OFF_BS + r0 + r];
        }
        float accP = 0.f;
        for (int t = tid; t < S; t += B) {
            float xt[D];
#pragma unroll
            for (int d = 0; d < D; ++d)
                xt[d] = ws[OFF_XST + (size_t)d * S + t];  // coalesced
            float nv = ws[OFF_TN + t];                     // precomputed |xt|^2
            float bt = ws[OFF_BS + t];
#pragma unroll
            for (int r = 0; r < ROWS; ++r) {
                float dot = 0.f;
#pragma unroll
                for (int d = 0; d < D; ++d) dot = fmaf(xr[r][d], xt[d], dot);
                float d2 = fmaxf(fmaf(-2.f, dot, nr[r] + nv), 0.f);
                float v = __expf(br[r] + bt - sqrtf(d2));
                accP += (r0 + r == t) ? 0.f : v;
            }
        }
        __syncthreads();
        float totP = block_reduce_sum(accP, sdata);
        if (tid == 0) ws[OFF_PD1 + bid] = totP;
    } else {
        int half_ = tid >> 1, q = tid & 1;
        const char* ep = reinterpret_cast<const char*>(ws + OFF_EP);
        float accE = 0.f;
        const int stride = GEDGE * 128;   // 128 edges per block per iter
        for (int e = (bid - GPAIR) * 128 + half_; e < E; e += stride) {
            int i = sparse_i[e], j = sparse_j[e];
            const char* ri = ep + (size_t)i * 64;
            const char* rj = ep + (size_t)j * 64;
            uint4 a = *reinterpret_cast<const uint4*>(ri + q * 16);
            uint4 b = *reinterpret_cast<const uint4*>(rj + q * 16);
            float part = qdiff8(a.x, a.y, a.z, a.w, b.x, b.y, b.z, b.w);
            part += __shfl_xor(part, 1, 2);
            if (q == 0) {
                float bi = *reinterpret_cast<const float*>(ri + 32);
                float bj = *reinterpret_cast<const float*>(rj + 32);
                accE += bi + bj - sqrtf(part);
            }
        }
        __syncthreads();
        float totE = block_reduce_sum(accE, sdata);
        if (tid == 0) ws[OFF_PD2 + (bid - GPAIR)] = totE;
    }
}

// K4 (1 block): final reduction (512 pairwise + 1024 edge partials).
__global__ __launch_bounds__(B) void k_fin(float* __restrict__ ws,
                                           float* __restrict__ out)
{
    __shared__ float sdata[256];
    int tid = threadIdx.x;
    float v1 = ws[OFF_PD1 + tid] + ws[OFF_PD1 + tid + 256];
    float s1 = block_reduce_sum(v1, sdata);
    __syncthreads();
    float v2 = ws[OFF_PD2 + tid] + ws[OFF_PD2 + tid + 256]
             + ws[OFF_PD2 + tid + 512] + ws[OFF_PD2 + tid + 768];
    float s2 = block_reduce_sum(v2, sdata);
    if (tid == 0) {
        float e = expf(1.0f);
        out[0] = s2 - 0.5f * e * e * s1;
    }
}

extern "C" void kernel_launch(void* const* d_in, const int* in_sizes, int n_in,
                              void* d_out, int out_size, void* d_ws, size_t ws_size,
                              hipStream_t stream) {
    const float* beta = (const float*)d_in[0];
    const float* A    = (const float*)d_in[1];
    const float* Zp   = (const float*)d_in[2];
    const float* Gate = (const float*)d_in[3];
    const int* sample_idx = (const int*)d_in[4];
    const int* sparse_i   = (const int*)d_in[5];
    const int* sparse_j   = (const int*)d_in[6];
    float* ws  = (float*)d_ws;
    float* out = (float*)d_out;

    k_ab <<<128, B, 0, stream>>>(Zp, Gate, sample_idx, A, ws);
    k_x  <<<320, B, 0, stream>>>(beta, sample_idx, ws);
    k_pe <<<GPE, B, 0, stream>>>(sparse_i, sparse_j, ws);
    k_fin<<<1,   B, 0, stream>>>(ws, out);
}

// Round 23
// 37.468 us; speedup vs baseline: 8.6987x; 1.0038x over previous
//
#include <hip/hip_runtime.h>
#include <hip/hip_fp16.h>
#include <math.h>

#define N 16384
#define K 32
#define D 16
#define S 2048
#define E 500000
#define EPSF 1e-6f
#define B 256

// ---- workspace layout (float offsets) ----
#define OFF_Z      0                       // K*N (col-major softmax result)
#define OFF_CSPART (K*N)                   // 64*32 colsum partials
#define OFF_AZCP   (OFF_CSPART + 2048)     // 64*512 partial AZC planes
#define OFF_EP     (OFF_AZCP + 32768)      // N rows x 64B: 16 fp16 dims + fp32 beta + pad
#define OFF_XST    (OFF_EP + N*16)         // D*S transposed samples (fp32, pairwise)
#define OFF_BS     (OFF_XST + D*S)         // S sampled betas
#define OFF_TN     (OFF_BS + S)            // S precomputed |xt|^2
#define OFF_PD1    (OFF_TN + S)            // 512 pairwise partials
#define OFF_PD2    (OFF_PD1 + 512)         // 1024 edge partials

#define GPAIR 512
#define GEDGE 1024
#define GPE   (GPAIR + GEDGE)
#define ROWS  4

__device__ __forceinline__ float block_reduce_sum(float v, float* sdata) {
    int tid = threadIdx.x;
    sdata[tid] = v;
    __syncthreads();
    for (int s = B >> 1; s > 0; s >>= 1) {
        if (tid < s) sdata[tid] += sdata[tid + s];
        __syncthreads();
    }
    return sdata[0];
}

// K1: blocks 0..63 softmax cols + ZTG colsum partials;
//     blocks 64..127: Mpart partials + per-block A@Mp -> AZCpart plane.
__global__ __launch_bounds__(B) void k_ab(
    const float* __restrict__ Zp, const float* __restrict__ Gate,
    const int* __restrict__ sample_idx, const float* __restrict__ A,
    float* __restrict__ ws)
{
    __shared__ __align__(16) float sf[256 * 33 + 256];
    int tid = threadIdx.x, bid = blockIdx.x;
    if (bid < 64) {
        int n = bid * B + tid;
        float z[K];
        float m = -1e30f;
#pragma unroll
        for (int k = 0; k < K; ++k) { z[k] = Zp[k * N + n]; m = fmaxf(m, z[k]); }
        float s = 0.f;
#pragma unroll
        for (int k = 0; k < K; ++k) { z[k] = __expf(z[k] - m); s += z[k]; }
        float inv = 1.f / s;
#pragma unroll
        for (int k = 0; k < K; ++k) { z[k] *= inv; ws[OFF_Z + k * N + n] = z[k]; }
        float t[K];
        const float4* gp = reinterpret_cast<const float4*>(Gate + (size_t)n * K);
#pragma unroll
        for (int q = 0; q < K / 4; ++q) {
            float4 g = gp[q];
            t[4*q+0] = z[4*q+0] / (1.f + __expf(-g.x));
            t[4*q+1] = z[4*q+1] / (1.f + __expf(-g.y));
            t[4*q+2] = z[4*q+2] / (1.f + __expf(-g.z));
            t[4*q+3] = z[4*q+3] / (1.f + __expf(-g.w));
        }
#pragma unroll
        for (int k = 0; k < K; ++k) sf[tid * 33 + k] = t[k];
        __syncthreads();
        int kk = tid & 31, rg = tid >> 5;
        float acc = 0.f;
#pragma unroll
        for (int r = 0; r < 32; ++r) acc += sf[(rg * 32 + r) * 33 + kk];
        sf[256 * 33 + rg * 32 + kk] = acc;
        __syncthreads();
        if (rg == 0) {
            float tot = 0.f;
#pragma unroll
            for (int g2 = 0; g2 < 8; ++g2) tot += sf[256 * 33 + g2 * 32 + kk];
            ws[OFF_CSPART + bid * 32 + kk] = tot;
        }
    } else {
        // 32 samples per block, 8 threads per sample -> Mp in LDS -> A@Mp plane
        float* sZ = sf;           // 32*32
        float* sT = sf + 1024;    // 32*32
        float* sM = sf + 2048;    // 32*32 (Mp)
        int slot = tid >> 3, sub = tid & 7;
        int idx = sample_idx[(bid - 64) * 32 + slot];
        float za[4];
        float m = -1e30f;
#pragma unroll
        for (int q = 0; q < 4; ++q) {
            za[q] = Zp[(sub + 8 * q) * N + idx];
            m = fmaxf(m, za[q]);
        }
#pragma unroll
        for (int off = 1; off < 8; off <<= 1) m = fmaxf(m, __shfl_xor(m, off, 8));
        float ssum = 0.f;
#pragma unroll
        for (int q = 0; q < 4; ++q) { za[q] = __expf(za[q] - m); ssum += za[q]; }
#pragma unroll
        for (int off = 1; off < 8; off <<= 1) ssum += __shfl_xor(ssum, off, 8);
        float inv = 1.f / ssum;
#pragma unroll
        for (int q = 0; q < 4; ++q) {
            int a = sub + 8 * q;
            float zv = za[q] * inv;
            float g = Gate[(size_t)idx * K + a];
            sZ[slot * 32 + a] = zv;
            sT[slot * 32 + a] = zv / (1.f + __expf(-g));
        }
        __syncthreads();
#pragma unroll
        for (int e4 = 0; e4 < 4; ++e4) {
            int ent = tid + e4 * B;
            int a = ent >> 5, b = ent & 31;
            float acc = 0.f;
#pragma unroll
            for (int sl = 0; sl < 32; ++sl) acc += sZ[sl * 32 + a] * sT[sl * 32 + b];
            sM[ent & 1023] = acc;
        }
        __syncthreads();
#pragma unroll
        for (int e2 = 0; e2 < 2; ++e2) {
            int ent = tid + e2 * B;
            int d = ent >> 5, b = ent & 31;
            float azc = 0.f;
#pragma unroll
            for (int a = 0; a < K; ++a) azc += A[d * K + a] * sM[a * 32 + b];
            ws[OFF_AZCP + (size_t)(bid - 64) * 512 + ent] = azc;
        }
    }
}

// K2 (grid 320): prologue reduces 64 AZCpart planes + colsum -> AZC in LDS.
// Blocks 0..255 -> packed edge rows (fp16 dims + fp32 beta, one 64B line/row);
// 256..319 -> XST (fp32 transposed samples) + bs + precomputed |xt|^2.
__global__ __launch_bounds__(B) void k_x(
    const float* __restrict__ beta, const int* __restrict__ sample_idx,
    float* __restrict__ ws)
{
    __shared__ float sA[512];
    __shared__ float scs[32];
    int tid = threadIdx.x, bid = blockIdx.x;
    if (tid < 32) {
        float cs = 0.f;
#pragma unroll
        for (int p = 0; p < 64; ++p) cs += ws[OFF_CSPART + p * 32 + tid];
        scs[tid] = cs;
    }
    float a0 = 0.f, a1 = 0.f;
#pragma unroll
    for (int p = 0; p < 64; ++p) {
        a0 += ws[OFF_AZCP + (size_t)p * 512 + tid];
        a1 += ws[OFF_AZCP + (size_t)p * 512 + tid + B];
    }
    __syncthreads();
    sA[tid]     = a0 / scs[tid & 31];
    sA[tid + B] = a1 / scs[tid & 31];
    __syncthreads();
    if (bid < 256) {
        int n = bid * 64 + (tid >> 2);
        int dq = tid & 3;
        float x0 = 0.f, x1 = 0.f, x2 = 0.f, x3 = 0.f;
#pragma unroll
        for (int k = 0; k < K; ++k) {
            float zk = ws[OFF_Z + k * N + n];
            x0 = fmaf(sA[(dq * 4 + 0) * 32 + k], zk, x0);
            x1 = fmaf(sA[(dq * 4 + 1) * 32 + k], zk, x1);
            x2 = fmaf(sA[(dq * 4 + 2) * 32 + k], zk, x2);
            x3 = fmaf(sA[(dq * 4 + 3) * 32 + k], zk, x3);
        }
        __half2 h01 = __floats2half2_rn(x0, x1);
        __half2 h23 = __floats2half2_rn(x2, x3);
        uint2 w;
        w.x = *reinterpret_cast<unsigned int*>(&h01);
        w.y = *reinterpret_cast<unsigned int*>(&h23);
        char* rowp = reinterpret_cast<char*>(ws + OFF_EP) + (size_t)n * 64;
        *reinterpret_cast<uint2*>(rowp + dq * 8) = w;
        if (dq == 0) *reinterpret_cast<float*>(rowp + 32) = beta[n];
    } else {
        int slot = tid >> 3, sub = tid & 7;
        int sslot = (bid - 256) * 32 + slot;
        int idx = sample_idx[sslot];
        float x0 = 0.f, x1 = 0.f;
#pragma unroll
        for (int k = 0; k < K; ++k) {
            float zk = ws[OFF_Z + (size_t)k * N + idx];
            x0 = fmaf(sA[(2 * sub + 0) * 32 + k], zk, x0);
            x1 = fmaf(sA[(2 * sub + 1) * 32 + k], zk, x1);
        }
        ws[OFF_XST + (size_t)(2 * sub + 0) * S + sslot] = x0;
        ws[OFF_XST + (size_t)(2 * sub + 1) * S + sslot] = x1;
        float nn = fmaf(x0, x0, x1 * x1);
        nn += __shfl_xor(nn, 1, 8);
        nn += __shfl_xor(nn, 2, 8);
        nn += __shfl_xor(nn, 4, 8);
        if (sub == 0) {
            ws[OFF_BS + sslot] = beta[idx];
            ws[OFF_TN + sslot] = nn;
        }
    }
}

// K3 (grid 1536): blocks 0..511 pairwise (4 rows in registers, precomputed
// t-norms); blocks 512..1535 edges: 2-lane scheme with PACKED half2 diff^2
// (4 hsub2 + 4 hfma2 per lane instead of 8 cvt + 8 scalar fma — edge loop
// was VALU-issue-bound at 83% busy, r21 probe). The reference's +1e-6 eps is
// below fp16 subnormal range and numerically invisible at the 8e5 tolerance.
__global__ __launch_bounds__(B) void k_pe(
    const int* __restrict__ sparse_i, const int* __restrict__ sparse_j,
    float* __restrict__ ws)
{
    __shared__ float sdata[256];
    int tid = threadIdx.x, bid = blockIdx.x;

    if (bid < GPAIR) {
        int r0 = bid * ROWS;
        float xr[ROWS][D];
        float nr[ROWS], br[ROWS];
#pragma unroll
        for (int r = 0; r < ROWS; ++r) {
            float nn = 0.f;
#pragma unroll
            for (int d = 0; d < D; ++d) {
                float v = ws[OFF_XST + (size_t)d * S + r0 + r] + EPSF;
                xr[r][d] = v;
                nn = fmaf(v, v, nn);
            }
            nr[r] = nn;
            br[r] = ws[OFF_BS + r0 + r];
        }
        float accP = 0.f;
        for (int t = tid; t < S; t += B) {
            float xt[D];
#pragma unroll
            for (int d = 0; d < D; ++d)
                xt[d] = ws[OFF_XST + (size_t)d * S + t];  // coalesced
            float nv = ws[OFF_TN + t];
            float bt = ws[OFF_BS + t];
#pragma unroll
            for (int r = 0; r < ROWS; ++r) {
                float dot = 0.f;
#pragma unroll
                for (int d = 0; d < D; ++d) dot = fmaf(xr[r][d], xt[d], dot);
                float d2 = fmaxf(fmaf(-2.f, dot, nr[r] + nv), 0.f);
                float v = __expf(br[r] + bt - sqrtf(d2));
                accP += (r0 + r == t) ? 0.f : v;
            }
        }
        __syncthreads();
        float totP = block_reduce_sum(accP, sdata);
        if (tid == 0) ws[OFF_PD1 + bid] = totP;
    } else {
        int half_ = tid >> 1, q = tid & 1;
        const char* ep = reinterpret_cast<const char*>(ws + OFF_EP);
        float accE = 0.f;
        const int stride = GEDGE * 128;   // 128 edges per block per iter
        for (int e = (bid - GPAIR) * 128 + half_; e < E; e += stride) {
            int i = sparse_i[e], j = sparse_j[e];
            const char* ri = ep + (size_t)i * 64;
            const char* rj = ep + (size_t)j * 64;
            uint4 a = *reinterpret_cast<const uint4*>(ri + q * 16);
            uint4 b = *reinterpret_cast<const uint4*>(rj + q * 16);
            __half2 acc2 = __half2half2(__ushort_as_half((unsigned short)0));
            __half2 d;
            d = __hsub2(*reinterpret_cast<__half2*>(&a.x),
                        *reinterpret_cast<__half2*>(&b.x));
            acc2 = __hfma2(d, d, acc2);
            d = __hsub2(*reinterpret_cast<__half2*>(&a.y),
                        *reinterpret_cast<__half2*>(&b.y));
            acc2 = __hfma2(d, d, acc2);
            d = __hsub2(*reinterpret_cast<__half2*>(&a.z),
                        *reinterpret_cast<__half2*>(&b.z));
            acc2 = __hfma2(d, d, acc2);
            d = __hsub2(*reinterpret_cast<__half2*>(&a.w),
                        *reinterpret_cast<__half2*>(&b.w));
            acc2 = __hfma2(d, d, acc2);
            float2 f2 = __half22float2(acc2);
            float part = f2.x + f2.y;
            part += __shfl_xor(part, 1, 2);
            if (q == 0) {
                float bi = *reinterpret_cast<const float*>(ri + 32);
                float bj = *reinterpret_cast<const float*>(rj + 32);
                accE += bi + bj - sqrtf(part);
            }
        }
        __syncthreads();
        float totE = block_reduce_sum(accE, sdata);
        if (tid == 0) ws[OFF_PD2 + (bid - GPAIR)] = totE;
    }
}

// K4 (1 block): final reduction (512 pairwise + 1024 edge partials).
__global__ __launch_bounds__(B) void k_fin(float* __restrict__ ws,
                                           float* __restrict__ out)
{
    __shared__ float sdata[256];
    int tid = threadIdx.x;
    float v1 = ws[OFF_PD1 + tid] + ws[OFF_PD1 + tid + 256];
    float s1 = block_reduce_sum(v1, sdata);
    __syncthreads();
    float v2 = ws[OFF_PD2 + tid] + ws[OFF_PD2 + tid + 256]
             + ws[OFF_PD2 + tid + 512] + ws[OFF_PD2 + tid + 768];
    float s2 = block_reduce_sum(v2, sdata);
    if (tid == 0) {
        float e = expf(1.0f);
        out[0] = s2 - 0.5f * e * e * s1;
    }
}

extern "C" void kernel_launch(void* const* d_in, const int* in_sizes, int n_in,
                              void* d_out, int out_size, void* d_ws, size_t ws_size,
                              hipStream_t stream) {
    const float* beta = (const float*)d_in[0];
    const float* A    = (const float*)d_in[1];
    const float* Zp   = (const float*)d_in[2];
    const float* Gate = (const float*)d_in[3];
    const int* sample_idx = (const int*)d_in[4];
    const int* sparse_i   = (const int*)d_in[5];
    const int* sparse_j   = (const int*)d_in[6];
    float* ws  = (float*)d_ws;
    float* out = (float*)d_out;

    k_ab <<<128, B, 0, stream>>>(Zp, Gate, sample_idx, A, ws);
    k_x  <<<320, B, 0, stream>>>(beta, sample_idx, ws);
    k_pe <<<GPE, B, 0, stream>>>(sparse_i, sparse_j, ws);
    k_fin<<<1,   B, 0, stream>>>(ws, out);
}